// Round 4
// baseline (1141.932 us; speedup 1.0000x reference)
//
#include <hip/hip_runtime.h>
#include <hip/hip_bf16.h>

// N=65536 points, H=256, 4 hidden layers, ReLU MLP -> (psi,p).
// ReLU => piecewise linear => Hessians vanish; f = p_x, g = p_y (RHO=1).
// Pipeline:
//   1) fp32 forward replicating np/BLAS arithmetic BIT-EXACTLY
//      (per-element sequential k-ascending FMA chain, bias added AFTER the
//      GEMM, relu mask = a > 0) -> exact reference masks + p   [VALU fp32]
//      v4: 8pts x 8cols register tile per thread (64 FMA per 48B LDS) to
//      move from LDS-BW-bound (~32% peak) to VALU-bound.
//   2) per-tangent (x, y) forward-mode chain: fp32 T storage,
//      hi/lo-split fp16 MFMA (fp32-quality GEMM)               [MFMA]
//   3) tiny epilogues: u,v (from Wout col 0), f,g (from Wout col 1)
// Workspace: bufA 64MB | bufB 64MB | masks 5x2MB | Wt_hi 512KB | Wt_lo 512KB

#define NPTS 65536
#define HDIM 256

typedef _Float16 half8_t __attribute__((ext_vector_type(8)));
typedef _Float16 half4_t __attribute__((ext_vector_type(4)));
typedef float floatx4 __attribute__((ext_vector_type(4)));

// ---------------------------------------------------------------- fused fp32 forward (np/BLAS-exact)
// 128 threads, 32 pts/block. hT[k][p] 32KB + Wpan 16KB (aliased w/ pscr) = 48KB
// -> 3 blocks/CU. Thread owns 8 pts x 8 cols (64 accumulators). Each output
// element is ONE sequential k-ascending fmaf chain from 0, bias added after
// (bit-exact vs np reference). Writes masks L0..L4 + p output.
__global__ void __launch_bounds__(128) fwd_fused_kernel(
    const float* __restrict__ x, const float* __restrict__ y, const float* __restrict__ t,
    const float* __restrict__ Win, const float* __restrict__ b_in,
    const float* __restrict__ Wh, const float* __restrict__ b_h,
    const float* __restrict__ Wout, const float* __restrict__ b_out,
    unsigned char* __restrict__ masks, float* __restrict__ out) {
  __shared__ float hT[256 * 32];       // [k][p] 32KB
  __shared__ float Wpan[16 * 256];     // [k][c] 16KB; reused as pscr at the end
  float* pscr = Wpan;                  // [pp][cgrp] stride 33 (needs 4224B)

  const int tid = threadIdx.x;
  const int pgrp = tid & 3;            // 4 groups of 8 points
  const int cgrp = tid >> 2;           // 32 groups of 8 cols
  const int p0 = blockIdx.x * 32;
  const int c0 = cgrp * 8;
  const int pb = pgrp * 8;

  // ---- layer 1: dot = z @ Win (k ascending: x,y,t), then + b_in  [bit-exact]
#pragma unroll
  for (int j = 0; j < 8; ++j) {
    int pp = pb + j;
    float xv = x[p0 + pp], yv = y[p0 + pp], tv = t[p0 + pp];
    unsigned m = 0;
#pragma unroll
    for (int e = 0; e < 8; ++e) {
      int c = c0 + e;
      float dot = fmaf(xv, Win[c], 0.f);
      dot = fmaf(yv, Win[256 + c], dot);
      dot = fmaf(tv, Win[512 + c], dot);
      float a = dot + b_in[c];
      bool pos = a > 0.f;
      hT[c * 32 + pp] = pos ? a : 0.f;
      m |= (pos ? 1u : 0u) << e;
    }
    masks[(size_t)(p0 + pp) * 32 + cgrp] = (unsigned char)m;
  }
  __syncthreads();

  // ---- hidden layers: single fp32 accumulator per element, k ascending, fmaf
  for (int l = 0; l < 4; ++l) {
    const float* Wl = Wh + (size_t)l * 65536;
    float acc[8][8] = {};              // [pt j][col e]
    for (int kp = 0; kp < 16; ++kp) {
      __syncthreads();                 // Wpan free to overwrite
      // stage W panel (16 k x 256 c = 16KB): pure linear copy
#pragma unroll
      for (int i = 0; i < 8; ++i) {
        int seg = tid + 128 * i;       // float4 index 0..1023
        *(float4*)&Wpan[seg * 4] = *(const float4*)(Wl + kp * 4096 + seg * 4);
      }
      __syncthreads();
#pragma unroll
      for (int k = 0; k < 16; ++k) {
        int kk = kp * 16 + k;
        float4 ha = *(const float4*)&hT[kk * 32 + pb];
        float4 hb = *(const float4*)&hT[kk * 32 + pb + 4];
        float4 w0 = *(const float4*)&Wpan[k * 256 + c0];
        float4 w1 = *(const float4*)&Wpan[k * 256 + c0 + 4];
        float hv[8] = {ha.x, ha.y, ha.z, ha.w, hb.x, hb.y, hb.z, hb.w};
        float wv[8] = {w0.x, w0.y, w0.z, w0.w, w1.x, w1.y, w1.z, w1.w};
#pragma unroll
        for (int j = 0; j < 8; ++j)
#pragma unroll
          for (int e = 0; e < 8; ++e)
            acc[j][e] = fmaf(hv[j], wv[e], acc[j][e]);
      }
    }
    __syncthreads();                   // all hT reads done before overwrite
    // epilogue: + bias (after), relu, mask bits, write back into hT
    float h5[8][8];
#pragma unroll
    for (int j = 0; j < 8; ++j) {
      int pp = pb + j;
      unsigned m = 0;
#pragma unroll
      for (int e = 0; e < 8; ++e) {
        float a = acc[j][e] + b_h[l * 256 + c0 + e];
        bool pos = a > 0.f;
        h5[j][e] = pos ? a : 0.f;
        m |= (pos ? 1u : 0u) << e;
      }
      masks[((size_t)(l + 1) * NPTS + (p0 + pp)) * 32 + cgrp] = (unsigned char)m;
    }
#pragma unroll
    for (int e = 0; e < 8; ++e) {      // write along p (two b128 per col)
      float4 v0 = {h5[0][e], h5[1][e], h5[2][e], h5[3][e]};
      float4 v1 = {h5[4][e], h5[5][e], h5[6][e], h5[7][e]};
      *(float4*)&hT[(c0 + e) * 32 + pb] = v0;
      *(float4*)&hT[(c0 + e) * 32 + pb + 4] = v1;
    }
    __syncthreads();
  }

  // ---- p = h5 . Wout[:,1] + b_out[1]  (value output; order-insensitive at
  //      bf16 comparison granularity) — pscr aliases Wpan (no longer needed)
#pragma unroll
  for (int j = 0; j < 8; ++j) {
    int pp = pb + j;
    float s = 0.f;
#pragma unroll
    for (int e = 0; e < 8; ++e)
      s = fmaf(hT[(c0 + e) * 32 + pp], Wout[2 * (c0 + e) + 1], s);
    pscr[pp * 33 + cgrp] = s;
  }
  __syncthreads();
  if (tid < 32) {
    float s = 0.f;
    for (int g = 0; g < 32; ++g) s += pscr[tid * 33 + g];
    out[2 * NPTS + p0 + tid] = s + b_out[1];
  }
}

// ---------------------------------------------------------------- prep: Wh fp32 [l][k][n] -> hi/lo f16 [l][n][k]
__global__ void __launch_bounds__(256) prep_weights_kernel(
    const float* __restrict__ Wh, _Float16* __restrict__ Whi, _Float16* __restrict__ Wlo) {
  int i = blockIdx.x * 256 + threadIdx.x;   // 0..262143
  int l = i >> 16;
  int rem = i & 65535;
  int k = rem >> 8, n = rem & 255;
  float w = Wh[i];
  _Float16 hi = (_Float16)w;
  _Float16 lo = (_Float16)((w - (float)hi) * 2048.f);
  size_t o = (size_t)(l << 16) + n * 256 + k;
  Whi[o] = hi;
  Wlo[o] = lo;
}

// ---------------------------------------------------------------- tangent init (fp32): T1 = mask1 .* Win-row
__global__ void __launch_bounds__(256) tangent_init_kernel(
    const float* __restrict__ WinRow, const unsigned char* __restrict__ mask1,
    float* __restrict__ T) {
  int p = blockIdx.x, c = threadIdx.x;
  bool m = (mask1[(size_t)p * 32 + (c >> 3)] >> (c & 7)) & 1;
  T[(size_t)p * 256 + c] = m ? WinRow[c] : 0.f;
}

// ---------------------------------------------------------------- tangent layer: Tout = (Tin @ W) .* mask
// fp32 in/out; hi/lo split f16 MFMA with second accumulator for 2048-scaled
// cross terms (full fp32-quality product). Block 128x128, 4 waves of 64x64.
// mfma_f32_16x16x32_f16: A[m=lane&15][k=quad*8+j], B[k=quad*8+j][n=lane&15],
//                        D[row=quad*4+reg][col=lane&15]
__global__ void __launch_bounds__(256, 2) tangent_gemm_kernel(
    const float* __restrict__ Tin,
    const _Float16* __restrict__ Whi, const _Float16* __restrict__ Wlo,  // [n][k]
    const unsigned int* __restrict__ maskDw,                             // [NPTS][8]
    float* __restrict__ Tout) {
  constexpr int SK = 72;  // lds row stride (halves)
  __shared__ alignas(16) _Float16 Ahi[128 * SK];
  __shared__ alignas(16) _Float16 Alo[128 * SK];
  __shared__ alignas(16) _Float16 Bhi[128 * SK];
  __shared__ alignas(16) _Float16 Blo[128 * SK];
  __shared__ unsigned int smask[128 * 8];

  const int tid = threadIdx.x;
  const int cb = blockIdx.x;   // 0..1
  const int rb = blockIdx.y;   // 0..511
  const int lane = tid & 63, wave = tid >> 6;
  const int wm = wave & 1, wn = wave >> 1;
  const int l15 = lane & 15, quad = lane >> 4;
  const int p0 = rb * 128;

#pragma unroll
  for (int i = 0; i < 4; ++i) {
    int idx = tid + 256 * i;
    smask[idx] = maskDw[(size_t)p0 * 8 + idx];
  }

  floatx4 acc1[4][4] = {};
  floatx4 acc2[4][4] = {};

  for (int kp = 0; kp < 4; ++kp) {
    __syncthreads();
    // stage A: fp32 -> hi/lo f16 (128 rows x 64 k)
#pragma unroll
    for (int i = 0; i < 8; ++i) {
      int j = tid + 256 * i;          // 0..2047 float4 segs
      int row = j >> 4, seg = j & 15;
      float4 v = *(const float4*)(Tin + (size_t)(p0 + row) * 256 + kp * 64 + seg * 4);
      half4_t h, lo;
      h[0] = (_Float16)v.x; h[1] = (_Float16)v.y; h[2] = (_Float16)v.z; h[3] = (_Float16)v.w;
      lo[0] = (_Float16)((v.x - (float)h[0]) * 2048.f);
      lo[1] = (_Float16)((v.y - (float)h[1]) * 2048.f);
      lo[2] = (_Float16)((v.z - (float)h[2]) * 2048.f);
      lo[3] = (_Float16)((v.w - (float)h[3]) * 2048.f);
      *(half4_t*)&Ahi[row * SK + seg * 4] = h;
      *(half4_t*)&Alo[row * SK + seg * 4] = lo;
    }
    // stage B: hi/lo f16 direct (128 n-rows x 64 k)
#pragma unroll
    for (int i = 0; i < 4; ++i) {
      int j = tid + 256 * i;          // 0..1023 half8 segs
      int row = j >> 3, seg = j & 7;
      *(half8_t*)&Bhi[row * SK + seg * 8] =
          *(const half8_t*)(Whi + (size_t)(cb * 128 + row) * 256 + kp * 64 + seg * 8);
      *(half8_t*)&Blo[row * SK + seg * 8] =
          *(const half8_t*)(Wlo + (size_t)(cb * 128 + row) * 256 + kp * 64 + seg * 8);
    }
    __syncthreads();
#pragma unroll
    for (int ks = 0; ks < 2; ++ks) {
      half8_t ah[4], al[4], bh[4], bl[4];
#pragma unroll
      for (int ti = 0; ti < 4; ++ti) {
        int r = (wm * 64 + ti * 16 + l15) * SK + ks * 32 + quad * 8;
        ah[ti] = *(const half8_t*)&Ahi[r];
        al[ti] = *(const half8_t*)&Alo[r];
      }
#pragma unroll
      for (int tj = 0; tj < 4; ++tj) {
        int r = (wn * 64 + tj * 16 + l15) * SK + ks * 32 + quad * 8;
        bh[tj] = *(const half8_t*)&Bhi[r];
        bl[tj] = *(const half8_t*)&Blo[r];
      }
#pragma unroll
      for (int ti = 0; ti < 4; ++ti)
#pragma unroll
        for (int tj = 0; tj < 4; ++tj) {
          acc1[ti][tj] = __builtin_amdgcn_mfma_f32_16x16x32_f16(ah[ti], bh[tj], acc1[ti][tj], 0, 0, 0);
          acc2[ti][tj] = __builtin_amdgcn_mfma_f32_16x16x32_f16(al[ti], bh[tj], acc2[ti][tj], 0, 0, 0);
          acc2[ti][tj] = __builtin_amdgcn_mfma_f32_16x16x32_f16(ah[ti], bl[tj], acc2[ti][tj], 0, 0, 0);
        }
    }
  }

  // epilogue: combine accs, mask-gate, fp32 store
#pragma unroll
  for (int ti = 0; ti < 4; ++ti) {
#pragma unroll
    for (int r = 0; r < 4; ++r) {
      int rloc = wm * 64 + ti * 16 + quad * 4 + r;
      size_t R = (size_t)p0 + rloc;
#pragma unroll
      for (int tj = 0; tj < 4; ++tj) {
        int C = cb * 128 + wn * 64 + tj * 16 + l15;
        float v = acc1[ti][tj][r] + acc2[ti][tj][r] * (1.f / 2048.f);
        unsigned int dw = smask[rloc * 8 + (C >> 5)];
        Tout[R * 256 + C] = ((dw >> (C & 31)) & 1u) ? v : 0.f;
      }
    }
  }
}

// ---------------------------------------------------------------- finalize one tangent: two dots with Wout cols
__global__ void __launch_bounds__(256) finalize_pass_kernel(
    const float* __restrict__ T5, const float* __restrict__ Wout,
    float* __restrict__ out, float sign0, int off0, int off1) {
  const int lane = threadIdx.x & 63;
  const int wave = threadIdx.x >> 6;
  const int p = blockIdx.x * 4 + wave;
  float4 h = *(const float4*)(T5 + (size_t)p * 256 + lane * 4);
  float4 wA = *(const float4*)(Wout + lane * 8);      // (W[c][0],W[c][1],W[c+1][0],W[c+1][1])
  float4 wB = *(const float4*)(Wout + lane * 8 + 4);
  float s0 = h.x * wA.x + h.y * wA.z + h.z * wB.x + h.w * wB.z;  // . Wout[:,0]
  float s1 = h.x * wA.y + h.y * wA.w + h.z * wB.y + h.w * wB.w;  // . Wout[:,1]
#pragma unroll
  for (int off = 1; off < 64; off <<= 1) {
    s0 += __shfl_xor(s0, off);
    s1 += __shfl_xor(s1, off);
  }
  if (lane == 0) {
    out[off0 + p] = sign0 * s0;
    out[off1 + p] = s1;
  }
}

// ---------------------------------------------------------------- launch
extern "C" void kernel_launch(void* const* d_in, const int* in_sizes, int n_in,
                              void* d_out, int out_size, void* d_ws, size_t ws_size,
                              hipStream_t stream) {
  const float* x = (const float*)d_in[0];
  const float* y = (const float*)d_in[1];
  const float* t = (const float*)d_in[2];
  const float* Win = (const float*)d_in[3];
  const float* b_in = (const float*)d_in[4];
  const float* Wh = (const float*)d_in[5];
  const float* b_h = (const float*)d_in[6];
  const float* Wout = (const float*)d_in[7];
  const float* b_out = (const float*)d_in[8];
  float* out = (float*)d_out;

  char* ws = (char*)d_ws;
  constexpr size_t BUF_SZ = (size_t)NPTS * 256 * 4;   // 64 MB fp32 tangent buffer
  constexpr size_t MASK_SZ = (size_t)NPTS * 32;       // 2 MB per layer
  float* bufA = (float*)ws;
  float* bufB = (float*)(ws + BUF_SZ);
  unsigned char* masks = (unsigned char*)(ws + 2 * BUF_SZ);
  _Float16* Wt_hi = (_Float16*)(ws + 2 * BUF_SZ + 5 * MASK_SZ);
  _Float16* Wt_lo = Wt_hi + 4 * 65536;

  // fp32 np-exact forward: masks L0..L4 + p
  fwd_fused_kernel<<<NPTS / 32, 128, 0, stream>>>(
      x, y, t, Win, b_in, Wh, b_h, Wout, b_out, masks, out);

  prep_weights_kernel<<<1024, 256, 0, stream>>>(Wh, Wt_hi, Wt_lo);

  // two tangent passes: s=0 -> x-tangent (v, f), s=1 -> y-tangent (u, g)
  for (int s = 0; s < 2; ++s) {
    tangent_init_kernel<<<NPTS, 256, 0, stream>>>(Win + s * 256, masks, bufA);
    float* Tin = bufA;
    float* To = bufB;
    dim3 ggrid(2, 512);
    for (int l = 0; l < 4; ++l) {
      tangent_gemm_kernel<<<ggrid, 256, 0, stream>>>(
          Tin, Wt_hi + (size_t)l * 65536, Wt_lo + (size_t)l * 65536,
          (const unsigned int*)(masks + (size_t)(l + 1) * MASK_SZ), To);
      float* tmp = Tin; Tin = To; To = tmp;
    }
    if (s == 0)
      finalize_pass_kernel<<<NPTS / 4, 256, 0, stream>>>(Tin, Wout, out, -1.f, NPTS, 3 * NPTS);
    else
      finalize_pass_kernel<<<NPTS / 4, 256, 0, stream>>>(Tin, Wout, out, 1.f, 0, 4 * NPTS);
  }
}

// Round 5
// 777.103 us; speedup vs baseline: 1.4695x; 1.4695x over previous
//
#include <hip/hip_runtime.h>
#include <hip/hip_bf16.h>

// N=65536 points, H=256, 4 hidden layers, ReLU MLP -> (psi,p).
// ReLU => piecewise linear => Hessians vanish; f = p_x, g = p_y (RHO=1).
// Pipeline:
//   1) fp32 forward replicating np/BLAS arithmetic BIT-EXACTLY
//      (per-element sequential k-ascending FMA chain, bias added AFTER,
//      relu mask = a > 0) -> exact reference masks + p   [VALU fp32]
//      v5: 512 thr / 64 pts / 4x8 reg tile; 80KB LDS -> 2 blocks/CU,
//      16 waves/CU (v4 died at 3.7 waves/CU).
//   2) fused 2-tangent forward-mode chain (x,y rows stacked, M=131072):
//      fp16 T storage, single fp16 MFMA per product         [MFMA]
//   3) tiny epilogue: u,v (Wout col 0), f,g (Wout col 1)
// Workspace: bufA 64MB | bufB 64MB | masks 5x2MB | Wt 512KB

#define NPTS 65536
#define HDIM 256

typedef _Float16 half8_t __attribute__((ext_vector_type(8)));
typedef _Float16 half4_t __attribute__((ext_vector_type(4)));
typedef float floatx4 __attribute__((ext_vector_type(4)));

// ---------------------------------------------------------------- fused fp32 forward (np/BLAS-exact)
// 512 threads, 64 pts/block. hT[k][p] 64KB + Wpan 16KB (aliased w/ pscr) = 80KB
// -> 2 blocks/CU, 16 waves/CU. Thread owns 4 pts x 8 cols (32 accumulators).
// Each output element is ONE sequential k-ascending fmaf chain from 0, bias
// added after (bit-exact vs np reference). Writes masks L0..L4 + p output.
__global__ void __launch_bounds__(512) fwd_fused_kernel(
    const float* __restrict__ x, const float* __restrict__ y, const float* __restrict__ t,
    const float* __restrict__ Win, const float* __restrict__ b_in,
    const float* __restrict__ Wh, const float* __restrict__ b_h,
    const float* __restrict__ Wout, const float* __restrict__ b_out,
    unsigned char* __restrict__ masks, float* __restrict__ out) {
  __shared__ float hT[256 * 64];       // [k][p] 64KB
  __shared__ float Wpan[16 * 256];     // [k][c] 16KB; reused as pscr at the end
  float* pscr = Wpan;                  // [pp][cgrp] stride 33 (needs 8448B <= 16KB)

  const int tid = threadIdx.x;
  const int pgrp = tid & 15;           // 16 groups of 4 points
  const int cgrp = tid >> 4;           // 32 groups of 8 cols
  const int p0 = blockIdx.x * 64;
  const int c0 = cgrp * 8;
  const int pb = pgrp * 4;

  // ---- layer 1: dot = z @ Win (k ascending: x,y,t), then + b_in  [bit-exact]
#pragma unroll
  for (int j = 0; j < 4; ++j) {
    int pp = pb + j;
    float xv = x[p0 + pp], yv = y[p0 + pp], tv = t[p0 + pp];
    unsigned m = 0;
#pragma unroll
    for (int e = 0; e < 8; ++e) {
      int c = c0 + e;
      float dot = fmaf(xv, Win[c], 0.f);
      dot = fmaf(yv, Win[256 + c], dot);
      dot = fmaf(tv, Win[512 + c], dot);
      float a = dot + b_in[c];
      bool pos = a > 0.f;
      hT[c * 64 + pp] = pos ? a : 0.f;
      m |= (pos ? 1u : 0u) << e;
    }
    masks[(size_t)(p0 + pp) * 32 + cgrp] = (unsigned char)m;
  }
  __syncthreads();

  // ---- hidden layers: single fp32 accumulator per element, k ascending, fmaf
  for (int l = 0; l < 4; ++l) {
    const float* Wl = Wh + (size_t)l * 65536;
    float acc[4][8] = {};              // [pt j][col e]
    for (int kp = 0; kp < 16; ++kp) {
      __syncthreads();                 // Wpan free to overwrite
      // stage W panel (16 k x 256 c = 16KB): pure linear copy, 2 float4/thread
#pragma unroll
      for (int i = 0; i < 2; ++i) {
        int seg = tid + 512 * i;       // float4 index 0..1023
        *(float4*)&Wpan[seg * 4] = *(const float4*)(Wl + kp * 4096 + seg * 4);
      }
      __syncthreads();
#pragma unroll
      for (int k = 0; k < 16; ++k) {
        int kk = kp * 16 + k;
        float4 ha = *(const float4*)&hT[kk * 64 + pb];
        float4 w0 = *(const float4*)&Wpan[k * 256 + c0];
        float4 w1 = *(const float4*)&Wpan[k * 256 + c0 + 4];
        float hv[4] = {ha.x, ha.y, ha.z, ha.w};
        float wv[8] = {w0.x, w0.y, w0.z, w0.w, w1.x, w1.y, w1.z, w1.w};
#pragma unroll
        for (int j = 0; j < 4; ++j)
#pragma unroll
          for (int e = 0; e < 8; ++e)
            acc[j][e] = fmaf(hv[j], wv[e], acc[j][e]);
      }
    }
    __syncthreads();                   // all hT reads done before overwrite
    // epilogue: + bias (after), relu, mask bits, write back into hT
    float h5[4][8];
#pragma unroll
    for (int j = 0; j < 4; ++j) {
      int pp = pb + j;
      unsigned m = 0;
#pragma unroll
      for (int e = 0; e < 8; ++e) {
        float a = acc[j][e] + b_h[l * 256 + c0 + e];
        bool pos = a > 0.f;
        h5[j][e] = pos ? a : 0.f;
        m |= (pos ? 1u : 0u) << e;
      }
      masks[((size_t)(l + 1) * NPTS + (p0 + pp)) * 32 + cgrp] = (unsigned char)m;
    }
#pragma unroll
    for (int e = 0; e < 8; ++e) {      // write along p (one b128 per col)
      float4 v0 = {h5[0][e], h5[1][e], h5[2][e], h5[3][e]};
      *(float4*)&hT[(c0 + e) * 64 + pb] = v0;
    }
    __syncthreads();
  }

  // ---- p = h5 . Wout[:,1] + b_out[1]  (value output; order-insensitive at
  //      bf16 comparison granularity) — pscr aliases Wpan
#pragma unroll
  for (int j = 0; j < 4; ++j) {
    int pp = pb + j;
    float s = 0.f;
#pragma unroll
    for (int e = 0; e < 8; ++e)
      s = fmaf(hT[(c0 + e) * 64 + pp], Wout[2 * (c0 + e) + 1], s);
    pscr[pp * 33 + cgrp] = s;
  }
  __syncthreads();
  if (tid < 64) {
    float s = 0.f;
    for (int g = 0; g < 32; ++g) s += pscr[tid * 33 + g];
    out[2 * NPTS + p0 + tid] = s + b_out[1];
  }
}

// ---------------------------------------------------------------- prep: Wh fp32 [l][k][n] -> f16 [l][n][k]
__global__ void __launch_bounds__(256) prep_weights_kernel(
    const float* __restrict__ Wh, _Float16* __restrict__ Wt) {
  int i = blockIdx.x * 256 + threadIdx.x;   // 0..262143
  int l = i >> 16;
  int rem = i & 65535;
  int k = rem >> 8, n = rem & 255;
  Wt[(size_t)(l << 16) + n * 256 + k] = (_Float16)Wh[i];
}

// ---------------------------------------------------------------- tangent init (fp16): both tangents stacked
__global__ void __launch_bounds__(256) tangent_init_kernel(
    const float* __restrict__ Win, const unsigned char* __restrict__ mask1,
    _Float16* __restrict__ T) {
  int p = blockIdx.x, c = threadIdx.x;
  bool m = (mask1[(size_t)p * 32 + (c >> 3)] >> (c & 7)) & 1;
  T[(size_t)p * 256 + c] = m ? (_Float16)Win[c] : (_Float16)0.f;          // x-tangent
  T[((size_t)NPTS + p) * 256 + c] = m ? (_Float16)Win[256 + c] : (_Float16)0.f;  // y-tangent
}

// ---------------------------------------------------------------- tangent layer: Tout = (Tin @ W) .* mask  (fp16 MFMA)
// M = 131072 rows (Tx then Ty), K = 256. Block 128x128, 4 waves of 64x64.
// mfma_f32_16x16x32_f16: A[m=lane&15][k=quad*8+j], B[k=quad*8+j][n=lane&15],
//                        D[row=quad*4+reg][col=lane&15]
__global__ void __launch_bounds__(256, 2) tangent_gemm_kernel(
    const _Float16* __restrict__ Tin,
    const _Float16* __restrict__ Wt,           // [n][k] (pre-transposed)
    const unsigned int* __restrict__ maskDw,   // [NPTS][8]
    _Float16* __restrict__ Tout) {
  constexpr int SK = 72;  // lds row stride (halves)
  __shared__ alignas(16) _Float16 Apan[128 * SK];
  __shared__ alignas(16) _Float16 Bpan[128 * SK];
  __shared__ unsigned int smask[128 * 8];

  const int tid = threadIdx.x;
  const int cb = blockIdx.x;   // 0..1
  const int rb = blockIdx.y;   // 0..1023
  const int lane = tid & 63, wave = tid >> 6;
  const int wm = wave & 1, wn = wave >> 1;
  const int l15 = lane & 15, quad = lane >> 4;
  const int p0 = (rb * 128) & (NPTS - 1);   // mask row (both halves share masks)

#pragma unroll
  for (int i = 0; i < 4; ++i) {
    int idx = tid + 256 * i;
    smask[idx] = maskDw[(size_t)p0 * 8 + idx];
  }

  floatx4 acc[4][4] = {};

  for (int kp = 0; kp < 4; ++kp) {
    __syncthreads();
    // stage A and B (128 rows x 64 k each), half8 vector loads
#pragma unroll
    for (int i = 0; i < 4; ++i) {
      int j = tid + 256 * i;       // 0..1023 half8 segs
      int row = j >> 3, seg = j & 7;
      *(half8_t*)&Apan[row * SK + seg * 8] =
          *(const half8_t*)(Tin + ((size_t)rb * 128 + row) * 256 + kp * 64 + seg * 8);
      *(half8_t*)&Bpan[row * SK + seg * 8] =
          *(const half8_t*)(Wt + ((size_t)(cb * 128 + row)) * 256 + kp * 64 + seg * 8);
    }
    __syncthreads();
#pragma unroll
    for (int ks = 0; ks < 2; ++ks) {
      half8_t af[4], bf[4];
#pragma unroll
      for (int ti = 0; ti < 4; ++ti)
        af[ti] = *(const half8_t*)&Apan[(wm * 64 + ti * 16 + l15) * SK + ks * 32 + quad * 8];
#pragma unroll
      for (int tj = 0; tj < 4; ++tj)
        bf[tj] = *(const half8_t*)&Bpan[(wn * 64 + tj * 16 + l15) * SK + ks * 32 + quad * 8];
#pragma unroll
      for (int ti = 0; ti < 4; ++ti)
#pragma unroll
        for (int tj = 0; tj < 4; ++tj)
          acc[ti][tj] = __builtin_amdgcn_mfma_f32_16x16x32_f16(af[ti], bf[tj], acc[ti][tj], 0, 0, 0);
    }
  }

  // epilogue: mask-gate, cast f16, store
#pragma unroll
  for (int ti = 0; ti < 4; ++ti) {
#pragma unroll
    for (int r = 0; r < 4; ++r) {
      int rloc = wm * 64 + ti * 16 + quad * 4 + r;
      size_t R = (size_t)rb * 128 + rloc;
#pragma unroll
      for (int tj = 0; tj < 4; ++tj) {
        int C = cb * 128 + wn * 64 + tj * 16 + l15;
        unsigned int dw = smask[rloc * 8 + (C >> 5)];
        float v = ((dw >> (C & 31)) & 1u) ? acc[ti][tj][r] : 0.f;
        Tout[R * 256 + C] = (_Float16)v;
      }
    }
  }
}

// ---------------------------------------------------------------- finalize: u, v, f, g from T5 (wave per point)
__global__ void __launch_bounds__(256) finalize_kernel(
    const _Float16* __restrict__ T5, const float* __restrict__ Wout,
    float* __restrict__ out) {
  const int lane = threadIdx.x & 63;
  const int wave = threadIdx.x >> 6;
  const int p = blockIdx.x * 4 + wave;
  half4_t hx = *(const half4_t*)(T5 + (size_t)p * 256 + lane * 4);
  half4_t hy = *(const half4_t*)(T5 + ((size_t)NPTS + p) * 256 + lane * 4);
  float4 wA = *(const float4*)(Wout + lane * 8);      // (W[c][0],W[c][1],W[c+1][0],W[c+1][1])
  float4 wB = *(const float4*)(Wout + lane * 8 + 4);
  float w0[4] = {wA.x, wA.z, wB.x, wB.z};  // Wout[:,0]
  float w1[4] = {wA.y, wA.w, wB.y, wB.w};  // Wout[:,1]
  float su = 0.f, sv = 0.f, sf = 0.f, sg = 0.f;
#pragma unroll
  for (int e = 0; e < 4; ++e) {
    float fx = (float)hx[e], fy = (float)hy[e];
    su = fmaf(fy, w0[e], su);
    sv = fmaf(-fx, w0[e], sv);
    sf = fmaf(fx, w1[e], sf);
    sg = fmaf(fy, w1[e], sg);
  }
#pragma unroll
  for (int off = 1; off < 64; off <<= 1) {
    su += __shfl_xor(su, off);
    sv += __shfl_xor(sv, off);
    sf += __shfl_xor(sf, off);
    sg += __shfl_xor(sg, off);
  }
  if (lane == 0) {
    out[p] = su;                 // u = dpsi/dy
    out[NPTS + p] = sv;          // v = -dpsi/dx
    out[3 * NPTS + p] = sf;      // f = p_x (RHO=1)
    out[4 * NPTS + p] = sg;      // g = p_y
  }
}

// ---------------------------------------------------------------- launch
extern "C" void kernel_launch(void* const* d_in, const int* in_sizes, int n_in,
                              void* d_out, int out_size, void* d_ws, size_t ws_size,
                              hipStream_t stream) {
  const float* x = (const float*)d_in[0];
  const float* y = (const float*)d_in[1];
  const float* t = (const float*)d_in[2];
  const float* Win = (const float*)d_in[3];
  const float* b_in = (const float*)d_in[4];
  const float* Wh = (const float*)d_in[5];
  const float* b_h = (const float*)d_in[6];
  const float* Wout = (const float*)d_in[7];
  const float* b_out = (const float*)d_in[8];
  float* out = (float*)d_out;

  char* ws = (char*)d_ws;
  constexpr size_t BUF_SZ = (size_t)NPTS * 256 * 4;   // 64 MB (holds 131072x256 f16)
  constexpr size_t MASK_SZ = (size_t)NPTS * 32;       // 2 MB per layer
  _Float16* bufA = (_Float16*)ws;
  _Float16* bufB = (_Float16*)(ws + BUF_SZ);
  unsigned char* masks = (unsigned char*)(ws + 2 * BUF_SZ);
  _Float16* Wt = (_Float16*)(ws + 2 * BUF_SZ + 5 * MASK_SZ);

  // fp32 np-exact forward: masks L0..L4 + p
  fwd_fused_kernel<<<NPTS / 64, 512, 0, stream>>>(
      x, y, t, Win, b_in, Wh, b_h, Wout, b_out, masks, out);

  prep_weights_kernel<<<1024, 256, 0, stream>>>(Wh, Wt);

  // fused 2-tangent chain (both x,y tangents stacked: M = 131072)
  tangent_init_kernel<<<NPTS, 256, 0, stream>>>(Win, masks, bufA);
  _Float16* Tin = bufA;
  _Float16* To = bufB;
  dim3 ggrid(2, 1024);
  for (int l = 0; l < 4; ++l) {
    tangent_gemm_kernel<<<ggrid, 256, 0, stream>>>(
        Tin, Wt + (size_t)l * 65536,
        (const unsigned int*)(masks + (size_t)(l + 1) * MASK_SZ), To);
    _Float16* tmp = Tin; Tin = To; To = tmp;
  }
  finalize_kernel<<<NPTS / 4, 256, 0, stream>>>(Tin, Wout, out);
}

// Round 6
// 705.885 us; speedup vs baseline: 1.6177x; 1.1009x over previous
//
#include <hip/hip_runtime.h>
#include <hip/hip_bf16.h>

// N=65536 points, H=256, 4 hidden layers, ReLU MLP -> (psi,p).
// ReLU => piecewise linear => Hessians vanish; f = p_x, g = p_y (RHO=1).
// Pipeline:
//   1) fp32 forward replicating np/BLAS arithmetic BIT-EXACTLY
//      (per-element sequential k-ascending FMA chain, bias added AFTER,
//      relu mask = a > 0) -> exact reference masks + p   [VALU fp32]
//      v6: lane=point, wave=32-col group -> W loads are wave-uniform
//      (scalar s_load, no LDS W panel, no staging barriers). hT[64][257]
//      fp32 in LDS (66.5KB) -> 2 blocks/CU, 16 waves/CU.
//   2) fused 2-tangent forward-mode chain (x,y rows stacked, M=131072):
//      fp16 T storage, single fp16 MFMA per product         [MFMA]
//   3) tiny epilogue: u,v (Wout col 0), f,g (Wout col 1)
// Workspace: bufA 64MB | bufB 64MB | masks 5x2MB | Wt 512KB

#define NPTS 65536
#define HDIM 256

typedef _Float16 half8_t __attribute__((ext_vector_type(8)));
typedef _Float16 half4_t __attribute__((ext_vector_type(4)));
typedef float floatx4 __attribute__((ext_vector_type(4)));

// ---------------------------------------------------------------- fused fp32 forward (np/BLAS-exact)
// 512 threads = 8 waves, 64 pts/block. lane = point, wave = 32-col group.
// W[k][c0..c0+31] is wave-uniform -> scalar cache (s_load), no W staging.
// hT[pt][k] stride 257 (odd -> bank-conflict-free b32). Each output element
// is ONE sequential k-ascending fmaf chain from 0, bias added after
// (bit-exact vs np reference). Writes masks L0..L4 + p output.
__global__ void __launch_bounds__(512) fwd_fused_kernel(
    const float* __restrict__ x, const float* __restrict__ y, const float* __restrict__ t,
    const float* __restrict__ Win, const float* __restrict__ b_in,
    const float* __restrict__ Wh, const float* __restrict__ b_h,
    const float* __restrict__ Wout, const float* __restrict__ b_out,
    unsigned char* __restrict__ masks, float* __restrict__ out) {
  constexpr int SH = 257;              // odd stride: banks (lane+k)%32, conflict-free
  __shared__ float hT[64 * SH];        // [pt][k]  65792 B
  __shared__ float pscr[8][72];        // wave partials for p (2304 B)

  const int tid = threadIdx.x;
  const int lane = tid & 63;                                    // point in block
  const int w = __builtin_amdgcn_readfirstlane(tid >> 6);       // wave id (uniform)
  const int c0 = w * 32;                                        // col group
  const int p0 = blockIdx.x * 64;
  const int p = p0 + lane;

  // ---- layer 1: dot = z @ Win (k ascending: x,y,t), then + b_in  [bit-exact]
  {
    float xv = x[p], yv = y[p], tv = t[p];
    unsigned m = 0;
#pragma unroll
    for (int e = 0; e < 32; ++e) {
      int c = c0 + e;                  // uniform -> Win reads are scalar
      float dot = fmaf(xv, Win[c], 0.f);
      dot = fmaf(yv, Win[256 + c], dot);
      dot = fmaf(tv, Win[512 + c], dot);
      float a = dot + b_in[c];
      bool pos = a > 0.f;
      hT[lane * SH + c] = pos ? a : 0.f;
      m |= (pos ? 1u : 0u) << e;
    }
    *(unsigned*)(masks + (size_t)p * 32 + w * 4) = m;
  }
  __syncthreads();

  // ---- hidden layers: single fp32 accumulator per element, k ascending, fmaf
  for (int l = 0; l < 4; ++l) {
    const float* Wl = Wh + (size_t)l * 65536 + c0;   // + uniform col offset
    float acc[32] = {};
#pragma unroll 2
    for (int k = 0; k < 256; ++k) {
      float h = hT[lane * SH + k];     // per-lane LDS, conflict-free
      const float* wr = Wl + k * 256;  // wave-uniform -> s_load_dwordx16
#pragma unroll
      for (int e = 0; e < 32; ++e)
        acc[e] = fmaf(h, wr[e], acc[e]);
    }
    __syncthreads();                   // all hT reads done before overwrite
    unsigned m = 0;
    float hnew[32];
#pragma unroll
    for (int e = 0; e < 32; ++e) {
      float a = acc[e] + b_h[l * 256 + c0 + e];
      bool pos = a > 0.f;
      hnew[e] = pos ? a : 0.f;
      m |= (pos ? 1u : 0u) << e;
    }
    *(unsigned*)(masks + ((size_t)(l + 1) * NPTS + p) * 32 + w * 4) = m;
#pragma unroll
    for (int e = 0; e < 32; ++e)
      hT[lane * SH + c0 + e] = hnew[e];
    __syncthreads();
  }

  // ---- p = h5 . Wout[:,1] + b_out[1]  (value output; order-insensitive at
  //      bf16 comparison granularity)
  float s = 0.f;
#pragma unroll
  for (int e = 0; e < 32; ++e)
    s = fmaf(hT[lane * SH + c0 + e], Wout[2 * (c0 + e) + 1], s);
  pscr[w][lane] = s;
  __syncthreads();
  if (tid < 64) {
    float s2 = 0.f;
#pragma unroll
    for (int g = 0; g < 8; ++g) s2 += pscr[g][tid];
    out[2 * NPTS + p0 + tid] = s2 + b_out[1];
  }
}

// ---------------------------------------------------------------- prep: Wh fp32 [l][k][n] -> f16 [l][n][k]
__global__ void __launch_bounds__(256) prep_weights_kernel(
    const float* __restrict__ Wh, _Float16* __restrict__ Wt) {
  int i = blockIdx.x * 256 + threadIdx.x;   // 0..262143
  int l = i >> 16;
  int rem = i & 65535;
  int k = rem >> 8, n = rem & 255;
  Wt[(size_t)(l << 16) + n * 256 + k] = (_Float16)Wh[i];
}

// ---------------------------------------------------------------- tangent init (fp16): both tangents stacked
__global__ void __launch_bounds__(256) tangent_init_kernel(
    const float* __restrict__ Win, const unsigned char* __restrict__ mask1,
    _Float16* __restrict__ T) {
  int p = blockIdx.x, c = threadIdx.x;
  bool m = (mask1[(size_t)p * 32 + (c >> 3)] >> (c & 7)) & 1;
  T[(size_t)p * 256 + c] = m ? (_Float16)Win[c] : (_Float16)0.f;          // x-tangent
  T[((size_t)NPTS + p) * 256 + c] = m ? (_Float16)Win[256 + c] : (_Float16)0.f;  // y-tangent
}

// ---------------------------------------------------------------- tangent layer: Tout = (Tin @ W) .* mask  (fp16 MFMA)
// M = 131072 rows (Tx then Ty), K = 256. Block 128x128, 4 waves of 64x64.
// mfma_f32_16x16x32_f16: A[m=lane&15][k=quad*8+j], B[k=quad*8+j][n=lane&15],
//                        D[row=quad*4+reg][col=lane&15]
__global__ void __launch_bounds__(256, 2) tangent_gemm_kernel(
    const _Float16* __restrict__ Tin,
    const _Float16* __restrict__ Wt,           // [n][k] (pre-transposed)
    const unsigned int* __restrict__ maskDw,   // [NPTS][8]
    _Float16* __restrict__ Tout) {
  constexpr int SK = 72;  // lds row stride (halves)
  __shared__ alignas(16) _Float16 Apan[128 * SK];
  __shared__ alignas(16) _Float16 Bpan[128 * SK];
  __shared__ unsigned int smask[128 * 8];

  const int tid = threadIdx.x;
  const int cb = blockIdx.x;   // 0..1
  const int rb = blockIdx.y;   // 0..1023
  const int lane = tid & 63, wave = tid >> 6;
  const int wm = wave & 1, wn = wave >> 1;
  const int l15 = lane & 15, quad = lane >> 4;
  const int p0 = (rb * 128) & (NPTS - 1);   // mask row (both halves share masks)

#pragma unroll
  for (int i = 0; i < 4; ++i) {
    int idx = tid + 256 * i;
    smask[idx] = maskDw[(size_t)p0 * 8 + idx];
  }

  floatx4 acc[4][4] = {};

  for (int kp = 0; kp < 4; ++kp) {
    __syncthreads();
    // stage A and B (128 rows x 64 k each), half8 vector loads
#pragma unroll
    for (int i = 0; i < 4; ++i) {
      int j = tid + 256 * i;       // 0..1023 half8 segs
      int row = j >> 3, seg = j & 7;
      *(half8_t*)&Apan[row * SK + seg * 8] =
          *(const half8_t*)(Tin + ((size_t)rb * 128 + row) * 256 + kp * 64 + seg * 8);
      *(half8_t*)&Bpan[row * SK + seg * 8] =
          *(const half8_t*)(Wt + ((size_t)(cb * 128 + row)) * 256 + kp * 64 + seg * 8);
    }
    __syncthreads();
#pragma unroll
    for (int ks = 0; ks < 2; ++ks) {
      half8_t af[4], bf[4];
#pragma unroll
      for (int ti = 0; ti < 4; ++ti)
        af[ti] = *(const half8_t*)&Apan[(wm * 64 + ti * 16 + l15) * SK + ks * 32 + quad * 8];
#pragma unroll
      for (int tj = 0; tj < 4; ++tj)
        bf[tj] = *(const half8_t*)&Bpan[(wn * 64 + tj * 16 + l15) * SK + ks * 32 + quad * 8];
#pragma unroll
      for (int ti = 0; ti < 4; ++ti)
#pragma unroll
        for (int tj = 0; tj < 4; ++tj)
          acc[ti][tj] = __builtin_amdgcn_mfma_f32_16x16x32_f16(af[ti], bf[tj], acc[ti][tj], 0, 0, 0);
    }
  }

  // epilogue: mask-gate, cast f16, store
#pragma unroll
  for (int ti = 0; ti < 4; ++ti) {
#pragma unroll
    for (int r = 0; r < 4; ++r) {
      int rloc = wm * 64 + ti * 16 + quad * 4 + r;
      size_t R = (size_t)rb * 128 + rloc;
#pragma unroll
      for (int tj = 0; tj < 4; ++tj) {
        int C = cb * 128 + wn * 64 + tj * 16 + l15;
        unsigned int dw = smask[rloc * 8 + (C >> 5)];
        float v = ((dw >> (C & 31)) & 1u) ? acc[ti][tj][r] : 0.f;
        Tout[R * 256 + C] = (_Float16)v;
      }
    }
  }
}

// ---------------------------------------------------------------- finalize: u, v, f, g from T5 (wave per point)
__global__ void __launch_bounds__(256) finalize_kernel(
    const _Float16* __restrict__ T5, const float* __restrict__ Wout,
    float* __restrict__ out) {
  const int lane = threadIdx.x & 63;
  const int wave = threadIdx.x >> 6;
  const int p = blockIdx.x * 4 + wave;
  half4_t hx = *(const half4_t*)(T5 + (size_t)p * 256 + lane * 4);
  half4_t hy = *(const half4_t*)(T5 + ((size_t)NPTS + p) * 256 + lane * 4);
  float4 wA = *(const float4*)(Wout + lane * 8);      // (W[c][0],W[c][1],W[c+1][0],W[c+1][1])
  float4 wB = *(const float4*)(Wout + lane * 8 + 4);
  float w0[4] = {wA.x, wA.z, wB.x, wB.z};  // Wout[:,0]
  float w1[4] = {wA.y, wA.w, wB.y, wB.w};  // Wout[:,1]
  float su = 0.f, sv = 0.f, sf = 0.f, sg = 0.f;
#pragma unroll
  for (int e = 0; e < 4; ++e) {
    float fx = (float)hx[e], fy = (float)hy[e];
    su = fmaf(fy, w0[e], su);
    sv = fmaf(-fx, w0[e], sv);
    sf = fmaf(fx, w1[e], sf);
    sg = fmaf(fy, w1[e], sg);
  }
#pragma unroll
  for (int off = 1; off < 64; off <<= 1) {
    su += __shfl_xor(su, off);
    sv += __shfl_xor(sv, off);
    sf += __shfl_xor(sf, off);
    sg += __shfl_xor(sg, off);
  }
  if (lane == 0) {
    out[p] = su;                 // u = dpsi/dy
    out[NPTS + p] = sv;          // v = -dpsi/dx
    out[3 * NPTS + p] = sf;      // f = p_x (RHO=1)
    out[4 * NPTS + p] = sg;      // g = p_y
  }
}

// ---------------------------------------------------------------- launch
extern "C" void kernel_launch(void* const* d_in, const int* in_sizes, int n_in,
                              void* d_out, int out_size, void* d_ws, size_t ws_size,
                              hipStream_t stream) {
  const float* x = (const float*)d_in[0];
  const float* y = (const float*)d_in[1];
  const float* t = (const float*)d_in[2];
  const float* Win = (const float*)d_in[3];
  const float* b_in = (const float*)d_in[4];
  const float* Wh = (const float*)d_in[5];
  const float* b_h = (const float*)d_in[6];
  const float* Wout = (const float*)d_in[7];
  const float* b_out = (const float*)d_in[8];
  float* out = (float*)d_out;

  char* ws = (char*)d_ws;
  constexpr size_t BUF_SZ = (size_t)NPTS * 256 * 4;   // 64 MB (holds 131072x256 f16)
  constexpr size_t MASK_SZ = (size_t)NPTS * 32;       // 2 MB per layer
  _Float16* bufA = (_Float16*)ws;
  _Float16* bufB = (_Float16*)(ws + BUF_SZ);
  unsigned char* masks = (unsigned char*)(ws + 2 * BUF_SZ);
  _Float16* Wt = (_Float16*)(ws + 2 * BUF_SZ + 5 * MASK_SZ);

  // fp32 np-exact forward: masks L0..L4 + p
  fwd_fused_kernel<<<NPTS / 64, 512, 0, stream>>>(
      x, y, t, Win, b_in, Wh, b_h, Wout, b_out, masks, out);

  prep_weights_kernel<<<1024, 256, 0, stream>>>(Wh, Wt);

  // fused 2-tangent chain (both x,y tangents stacked: M = 131072)
  tangent_init_kernel<<<NPTS, 256, 0, stream>>>(Win, masks, bufA);
  _Float16* Tin = bufA;
  _Float16* To = bufB;
  dim3 ggrid(2, 1024);
  for (int l = 0; l < 4; ++l) {
    tangent_gemm_kernel<<<ggrid, 256, 0, stream>>>(
        Tin, Wt + (size_t)l * 65536,
        (const unsigned int*)(masks + (size_t)(l + 1) * MASK_SZ), To);
    _Float16* tmp = Tin; Tin = To; To = tmp;
  }
  finalize_kernel<<<NPTS / 4, 256, 0, stream>>>(Tin, Wout, out);
}

// Round 7
// 599.147 us; speedup vs baseline: 1.9059x; 1.1781x over previous
//
#include <hip/hip_runtime.h>
#include <hip/hip_bf16.h>

// N=65536 points, H=256, 4 hidden layers, ReLU MLP -> (psi,p).
// ReLU => piecewise linear => Hessians vanish; f = p_x, g = p_y (RHO=1).
// Pipeline:
//   1) fp32 forward replicating np/BLAS arithmetic BIT-EXACTLY (v6 kernel,
//      lane=point / wave=32-col scalar-weight mapping) -> masks + p [VALU]
//   2) v7: ONE fused tangent kernel: T1 init from masks+Win, 4 MFMA layers
//      with mask-gated f16 LDS roundtrip (T never touches HBM), fused
//      finalize -> u,v,f,g. Block = 32 pts x 2 tangents = 64 rows x 256 cols.
// Workspace: masks 5x2MB | Wt 512KB

#define NPTS 65536
#define HDIM 256

typedef _Float16 half8_t __attribute__((ext_vector_type(8)));
typedef _Float16 half4_t __attribute__((ext_vector_type(4)));
typedef float floatx4 __attribute__((ext_vector_type(4)));

// ---------------------------------------------------------------- fused fp32 forward (np/BLAS-exact) — unchanged v6
__global__ void __launch_bounds__(512) fwd_fused_kernel(
    const float* __restrict__ x, const float* __restrict__ y, const float* __restrict__ t,
    const float* __restrict__ Win, const float* __restrict__ b_in,
    const float* __restrict__ Wh, const float* __restrict__ b_h,
    const float* __restrict__ Wout, const float* __restrict__ b_out,
    unsigned char* __restrict__ masks, float* __restrict__ out) {
  constexpr int SH = 257;              // odd stride: conflict-free b32
  __shared__ float hT[64 * SH];        // [pt][k]  65792 B
  __shared__ float pscr[8][72];

  const int tid = threadIdx.x;
  const int lane = tid & 63;                                    // point in block
  const int w = __builtin_amdgcn_readfirstlane(tid >> 6);       // wave id (uniform)
  const int c0 = w * 32;
  const int p0 = blockIdx.x * 64;
  const int p = p0 + lane;

  // layer 1: dot = z @ Win (k ascending: x,y,t), then + b_in  [bit-exact]
  {
    float xv = x[p], yv = y[p], tv = t[p];
    unsigned m = 0;
#pragma unroll
    for (int e = 0; e < 32; ++e) {
      int c = c0 + e;
      float dot = fmaf(xv, Win[c], 0.f);
      dot = fmaf(yv, Win[256 + c], dot);
      dot = fmaf(tv, Win[512 + c], dot);
      float a = dot + b_in[c];
      bool pos = a > 0.f;
      hT[lane * SH + c] = pos ? a : 0.f;
      m |= (pos ? 1u : 0u) << e;
    }
    *(unsigned*)(masks + (size_t)p * 32 + w * 4) = m;
  }
  __syncthreads();

  for (int l = 0; l < 4; ++l) {
    const float* Wl = Wh + (size_t)l * 65536 + c0;
    float acc[32] = {};
#pragma unroll 2
    for (int k = 0; k < 256; ++k) {
      float h = hT[lane * SH + k];
      const float* wr = Wl + k * 256;   // wave-uniform -> s_load
#pragma unroll
      for (int e = 0; e < 32; ++e)
        acc[e] = fmaf(h, wr[e], acc[e]);
    }
    __syncthreads();
    unsigned m = 0;
    float hnew[32];
#pragma unroll
    for (int e = 0; e < 32; ++e) {
      float a = acc[e] + b_h[l * 256 + c0 + e];
      bool pos = a > 0.f;
      hnew[e] = pos ? a : 0.f;
      m |= (pos ? 1u : 0u) << e;
    }
    *(unsigned*)(masks + ((size_t)(l + 1) * NPTS + p) * 32 + w * 4) = m;
#pragma unroll
    for (int e = 0; e < 32; ++e)
      hT[lane * SH + c0 + e] = hnew[e];
    __syncthreads();
  }

  float s = 0.f;
#pragma unroll
  for (int e = 0; e < 32; ++e)
    s = fmaf(hT[lane * SH + c0 + e], Wout[2 * (c0 + e) + 1], s);
  pscr[w][lane] = s;
  __syncthreads();
  if (tid < 64) {
    float s2 = 0.f;
#pragma unroll
    for (int g = 0; g < 8; ++g) s2 += pscr[g][tid];
    out[2 * NPTS + p0 + tid] = s2 + b_out[1];
  }
}

// ---------------------------------------------------------------- prep: Wh fp32 [l][k][n] -> f16 [l][n][k]
__global__ void __launch_bounds__(256) prep_weights_kernel(
    const float* __restrict__ Wh, _Float16* __restrict__ Wt) {
  int i = blockIdx.x * 256 + threadIdx.x;   // 0..262143
  int l = i >> 16;
  int rem = i & 65535;
  int k = rem >> 8, n = rem & 255;
  Wt[(size_t)(l << 16) + n * 256 + k] = (_Float16)Wh[i];
}

// ---------------------------------------------------------------- fused tangent chain (init + 4 layers + finalize)
// Block: 256 thr = 4 waves. 32 points -> 64 rows (0..31 x-tangent, 32..63 y).
// Tile M=64 x N=256; wave wn owns 64 rows x 64 cols (acc 4x4 16x16 tiles).
// T lives in Apan (f16) across layers; W streamed in 64-k chunks to Bpan.
// mfma_f32_16x16x32_f16: A[m=lane&15][k=quad*8+j], B[k=quad*8+j][n=lane&15],
//                        D[row=quad*4+reg][col=lane&15]  (verified layouts)
__global__ void __launch_bounds__(256, 2) tangent_fused_kernel(
    const float* __restrict__ Win,
    const _Float16* __restrict__ Wt,          // [l][n][k] (pre-transposed)
    const unsigned int* __restrict__ maskDw,  // [5][NPTS][8] dwords
    const float* __restrict__ Wout, float* __restrict__ out) {
  constexpr int SA = 264;   // A row stride (halves): 256 + 8 pad
  constexpr int SB = 72;    // B row stride (halves): 64 + 8 pad
  __shared__ alignas(16) _Float16 Apan[64 * SA];    // 33792 B
  __shared__ alignas(16) _Float16 Bpan[256 * SB];   // 36864 B
  __shared__ unsigned int smask[5 * 256];           // 5120 B

  const int tid = threadIdx.x;
  const int lane = tid & 63;
  const int wn = tid >> 6;          // wave = 64-col group
  const int l15 = lane & 15, quad = lane >> 4;
  const int p0 = blockIdx.x * 32;   // 32 points per block

  // ---- stage all 5 mask layers (32 pts x 8 dw each)
#pragma unroll
  for (int i = 0; i < 5; ++i)
    smask[i * 256 + tid] = maskDw[(size_t)i * NPTS * 8 + (size_t)p0 * 8 + tid];
  __syncthreads();

  // ---- init T1 into Apan: row<32 -> x-tangent (Win row 0), row>=32 -> y (row 1)
#pragma unroll
  for (int i = 0; i < 8; ++i) {
    int g = tid + 256 * i;          // 0..2047 col-groups of 8
    int row = g >> 5, cg = g & 31;
    int c0 = cg * 8, pt = row & 31, tg = row >> 5;
    unsigned dw = smask[pt * 8 + (c0 >> 5)];
    half8_t v;
#pragma unroll
    for (int e = 0; e < 8; ++e) {
      bool m = (dw >> ((cg & 3) * 8 + e)) & 1;
      v[e] = m ? (_Float16)Win[tg * 256 + c0 + e] : (_Float16)0.f;
    }
    *(half8_t*)&Apan[row * SA + c0] = v;
  }

  // ---- 4 layers: acc = A @ W_l, gate by mask[l+1], back into Apan as f16
  for (int l = 0; l < 4; ++l) {
    const _Float16* Wl = Wt + (size_t)l * 65536;
    floatx4 acc[4][4] = {};   // [mi][nj]
    for (int kp = 0; kp < 4; ++kp) {
      __syncthreads();        // Bpan free (and Apan init/writes visible)
      // stage B chunk: 256 n-rows x 64 k halves
#pragma unroll
      for (int i = 0; i < 8; ++i) {
        int g = tid + 256 * i;      // 0..2047 half8 segs
        int row = g >> 3, seg = g & 7;
        *(half8_t*)&Bpan[row * SB + seg * 8] =
            *(const half8_t*)(Wl + (size_t)row * 256 + kp * 64 + seg * 8);
      }
      __syncthreads();
#pragma unroll
      for (int ks = 0; ks < 2; ++ks) {
        half8_t af[4], bf[4];
#pragma unroll
        for (int mi = 0; mi < 4; ++mi)
          af[mi] = *(const half8_t*)&Apan[(mi * 16 + l15) * SA + kp * 64 + ks * 32 + quad * 8];
#pragma unroll
        for (int nj = 0; nj < 4; ++nj)
          bf[nj] = *(const half8_t*)&Bpan[(wn * 64 + nj * 16 + l15) * SB + ks * 32 + quad * 8];
#pragma unroll
        for (int mi = 0; mi < 4; ++mi)
#pragma unroll
          for (int nj = 0; nj < 4; ++nj)
            acc[mi][nj] = __builtin_amdgcn_mfma_f32_16x16x32_f16(af[mi], bf[nj], acc[mi][nj], 0, 0, 0);
      }
    }
    __syncthreads();          // all Apan reads of this layer done
    // gated write-back (C layout -> A storage), f16
    const unsigned int* ml = &smask[(l + 1) * 256];
#pragma unroll
    for (int mi = 0; mi < 4; ++mi) {
#pragma unroll
      for (int r = 0; r < 4; ++r) {
        int row = mi * 16 + quad * 4 + r;
        int pt = row & 31;
#pragma unroll
        for (int nj = 0; nj < 4; ++nj) {
          int C = wn * 64 + nj * 16 + l15;
          bool m = (ml[pt * 8 + (C >> 5)] >> (C & 31)) & 1;
          Apan[row * SA + C] = m ? (_Float16)acc[mi][nj][r] : (_Float16)0.f;
        }
      }
    }
    __syncthreads();
  }

  // ---- finalize from Apan (= T5 gated): per row, dots with Wout cols
  float4 wA = *(const float4*)(Wout + lane * 8);      // (W[c][0],W[c][1],W[c+1][0],W[c+1][1])
  float4 wB = *(const float4*)(Wout + lane * 8 + 4);
  float w0[4] = {wA.x, wA.z, wB.x, wB.z};  // Wout[:,0] for cols lane*4..+3
  float w1[4] = {wA.y, wA.w, wB.y, wB.w};  // Wout[:,1]
#pragma unroll
  for (int i = 0; i < 16; ++i) {
    int row = wn * 16 + i;
    half4_t hv = *(const half4_t*)&Apan[row * SA + lane * 4];
    float s0 = 0.f, s1 = 0.f;
#pragma unroll
    for (int e = 0; e < 4; ++e) {
      float fv = (float)hv[e];
      s0 = fmaf(fv, w0[e], s0);
      s1 = fmaf(fv, w1[e], s1);
    }
#pragma unroll
    for (int off = 1; off < 64; off <<= 1) {
      s0 += __shfl_xor(s0, off);
      s1 += __shfl_xor(s1, off);
    }
    if (lane == 0) {
      int pt = p0 + (row & 31);
      if (row < 32) {                 // x-tangent: v = -psi_x, f = p_x
        out[NPTS + pt] = -s0;
        out[3 * NPTS + pt] = s1;
      } else {                        // y-tangent: u = psi_y, g = p_y
        out[pt] = s0;
        out[4 * NPTS + pt] = s1;
      }
    }
  }
}

// ---------------------------------------------------------------- launch
extern "C" void kernel_launch(void* const* d_in, const int* in_sizes, int n_in,
                              void* d_out, int out_size, void* d_ws, size_t ws_size,
                              hipStream_t stream) {
  const float* x = (const float*)d_in[0];
  const float* y = (const float*)d_in[1];
  const float* t = (const float*)d_in[2];
  const float* Win = (const float*)d_in[3];
  const float* b_in = (const float*)d_in[4];
  const float* Wh = (const float*)d_in[5];
  const float* b_h = (const float*)d_in[6];
  const float* Wout = (const float*)d_in[7];
  const float* b_out = (const float*)d_in[8];
  float* out = (float*)d_out;

  char* ws = (char*)d_ws;
  constexpr size_t MASK_SZ = (size_t)NPTS * 32;       // 2 MB per layer
  unsigned char* masks = (unsigned char*)ws;
  _Float16* Wt = (_Float16*)(ws + 5 * MASK_SZ);

  // weight transpose/cast first (independent of fwd)
  prep_weights_kernel<<<1024, 256, 0, stream>>>(Wh, Wt);

  // fp32 np-exact forward: masks L0..L4 + p
  fwd_fused_kernel<<<NPTS / 64, 512, 0, stream>>>(
      x, y, t, Win, b_in, Wh, b_h, Wout, b_out, masks, out);

  // fused tangent chain: init + 4 MFMA layers + finalize (u,v,f,g)
  tangent_fused_kernel<<<NPTS / 32, 256, 0, stream>>>(
      Win, Wt, (const unsigned int*)masks, Wout, out);
}